// Round 1
// baseline (885.336 us; speedup 1.0000x reference)
//
#include <hip/hip_runtime.h>
#include <math.h>

#define NN 100000
#define NE 1600000

// ---------------- helpers ----------------
static __device__ __forceinline__ void fma4(float4& c, float a, const float4& w) {
    c.x += a * w.x; c.y += a * w.y; c.z += a * w.z; c.w += a * w.w;
}

// ---------------- CSR build ----------------
__global__ void k_count_deg(const int* __restrict__ dst, int* __restrict__ deg) {
    int e = blockIdx.x * blockDim.x + threadIdx.x;
    if (e < NE) atomicAdd(&deg[dst[e]], 1);
}

// single-block exclusive scan of deg[NN] -> offs[NN]
__global__ __launch_bounds__(1024) void k_scan(const int* __restrict__ deg, int* __restrict__ offs) {
    __shared__ int sums[1024];
    const int CH = (NN + 1023) / 1024;  // 98
    int t = threadIdx.x;
    int base = t * CH;
    int s = 0;
    for (int i = 0; i < CH; ++i) {
        int idx = base + i;
        if (idx < NN) s += deg[idx];
    }
    sums[t] = s;
    __syncthreads();
    // Hillis-Steele inclusive scan
    for (int d = 1; d < 1024; d <<= 1) {
        int v = (t >= d) ? sums[t - d] : 0;
        __syncthreads();
        sums[t] += v;
        __syncthreads();
    }
    int run = (t == 0) ? 0 : sums[t - 1];
    for (int i = 0; i < CH; ++i) {
        int idx = base + i;
        if (idx < NN) { offs[idx] = run; run += deg[idx]; }
    }
}

__global__ void k_fill(const int* __restrict__ src, const int* __restrict__ dst,
                       const int* __restrict__ offs, int* __restrict__ cur,
                       int* __restrict__ csr) {
    int e = blockIdx.x * blockDim.x + threadIdx.x;
    if (e < NE) {
        int d = dst[e];
        int p = atomicAdd(&cur[d], 1);
        csr[offs[d] + p] = src[e];
    }
}

// ---------------- mean aggregation: one wave per node ----------------
__global__ __launch_bounds__(256)
void k_aggregate(const float* __restrict__ feat, const int* __restrict__ csr,
                 const int* __restrict__ offs, const int* __restrict__ deg,
                 float* __restrict__ outmean) {
    int wid = threadIdx.x >> 6;
    int lane = threadIdx.x & 63;
    int node = blockIdx.x * 4 + wid;
    if (node >= NN) return;
    int off = offs[node];
    int dg = deg[node];
    float ax = 0.f, ay = 0.f;
    const float2* f2 = (const float2*)feat;
    for (int j = 0; j < dg; ++j) {
        int s = csr[off + j];
        float2 v = f2[(size_t)s * 64 + lane];
        ax += v.x; ay += v.y;
    }
    float inv = 1.0f / (float)(dg > 0 ? dg : 1);
    float2* o2 = (float2*)outmean;
    o2[(size_t)node * 64 + lane] = make_float2(ax * inv, ay * inv);
}

// ---------------- fused dual GEMM: out = Am@Wl + Ax@Wr + bias (+relu) ----------------
// M=NN, K=128, N=BN (128 or 64). Block: 64 rows x BN cols, 256 threads.
template <int BN, bool RELU>
__global__ __launch_bounds__(256)
void k_gemm(const float* __restrict__ Am, const float* __restrict__ Ax,
            const float* __restrict__ Wl, const float* __restrict__ Wr,
            const float* __restrict__ bias, float* __restrict__ out) {
    constexpr int NH = BN / 64;   // column halves per thread
    constexpr int F  = BN / 8;    // floats of W loaded per thread per chunk
    __shared__ float Alds[64][33];
    __shared__ float Wlds[32][BN];

    const int tid = threadIdx.x;
    const int tx = tid & 15;      // 16 col groups
    const int ty = tid >> 4;      // 16 row groups
    const int row0 = blockIdx.x * 64;

    float4 acc[4][NH];
    #pragma unroll
    for (int i = 0; i < 4; ++i)
        #pragma unroll
        for (int hh = 0; hh < NH; ++hh) acc[i][hh] = make_float4(0.f, 0.f, 0.f, 0.f);

    const int lr = tid >> 2;          // A-load row 0..63
    const int lc = (tid & 3) * 8;     // A-load col 0/8/16/24
    const int wk = tid >> 3;          // W-load row 0..31
    const int wc = (tid & 7) * F;     // W-load col

    for (int s = 0; s < 2; ++s) {
        const float* __restrict__ A = s ? Ax : Am;
        const float* __restrict__ W = s ? Wr : Wl;
        for (int kc = 0; kc < 128; kc += 32) {
            float4 a0 = make_float4(0.f,0.f,0.f,0.f), a1 = a0;
            int grow = row0 + lr;
            if (grow < NN) {
                const float* p = &A[(size_t)grow * 128 + kc + lc];
                a0 = *(const float4*)p;
                a1 = *(const float4*)(p + 4);
            }
            float4 wv[F / 4];
            {
                const float* wp = &W[(size_t)(wk + kc) * BN + wc];
                #pragma unroll
                for (int j = 0; j < F / 4; ++j) wv[j] = *(const float4*)(wp + 4 * j);
            }
            __syncthreads();  // previous chunk's LDS reads done before overwrite
            Alds[lr][lc+0]=a0.x; Alds[lr][lc+1]=a0.y; Alds[lr][lc+2]=a0.z; Alds[lr][lc+3]=a0.w;
            Alds[lr][lc+4]=a1.x; Alds[lr][lc+5]=a1.y; Alds[lr][lc+6]=a1.z; Alds[lr][lc+7]=a1.w;
            #pragma unroll
            for (int j = 0; j < F / 4; ++j) *(float4*)&Wlds[wk][wc + 4 * j] = wv[j];
            __syncthreads();
            #pragma unroll
            for (int kk = 0; kk < 32; ++kk) {
                float r0 = Alds[ty*4+0][kk];
                float r1 = Alds[ty*4+1][kk];
                float r2 = Alds[ty*4+2][kk];
                float r3 = Alds[ty*4+3][kk];
                #pragma unroll
                for (int hh = 0; hh < NH; ++hh) {
                    float4 w = *(const float4*)&Wlds[kk][hh*64 + tx*4];
                    fma4(acc[0][hh], r0, w);
                    fma4(acc[1][hh], r1, w);
                    fma4(acc[2][hh], r2, w);
                    fma4(acc[3][hh], r3, w);
                }
            }
        }
    }
    // epilogue
    #pragma unroll
    for (int hh = 0; hh < NH; ++hh) {
        float4 b = *(const float4*)&bias[hh*64 + tx*4];
        #pragma unroll
        for (int i = 0; i < 4; ++i) {
            int r = row0 + ty*4 + i;
            if (r < NN) {
                float4 v = acc[i][hh];
                v.x += b.x; v.y += b.y; v.z += b.z; v.w += b.w;
                if (RELU) {
                    v.x = fmaxf(v.x, 0.f); v.y = fmaxf(v.y, 0.f);
                    v.z = fmaxf(v.z, 0.f); v.w = fmaxf(v.w, 0.f);
                }
                *(float4*)&out[(size_t)r * BN + hh*64 + tx*4] = v;
            }
        }
    }
}

// ---------------- log_softmax over 64 cols, one wave per row ----------------
__global__ __launch_bounds__(256)
void k_logsoftmax(float* __restrict__ out) {
    int wid = threadIdx.x >> 6, lane = threadIdx.x & 63;
    int row = blockIdx.x * 4 + wid;
    if (row >= NN) return;
    float v = out[(size_t)row * 64 + lane];
    float m = v;
    #pragma unroll
    for (int d = 32; d >= 1; d >>= 1) m = fmaxf(m, __shfl_xor(m, d));
    float ev = __expf(v - m);
    float ssum = ev;
    #pragma unroll
    for (int d = 32; d >= 1; d >>= 1) ssum += __shfl_xor(ssum, d);
    out[(size_t)row * 64 + lane] = v - m - logf(ssum);
}

// ---------------- launch ----------------
extern "C" void kernel_launch(void* const* d_in, const int* in_sizes, int n_in,
                              void* d_out, int out_size, void* d_ws, size_t ws_size,
                              hipStream_t stream) {
    const float* x   = (const float*)d_in[0];
    const int* edges = (const int*)d_in[1];
    const float* W1l = (const float*)d_in[2];
    const float* b1  = (const float*)d_in[3];
    const float* W1r = (const float*)d_in[4];
    const float* W2l = (const float*)d_in[5];
    const float* b2  = (const float*)d_in[6];
    const float* W2r = (const float*)d_in[7];
    float* out = (float*)d_out;

    const int* src = edges;            // edge_index[0]
    const int* dst = edges + NE;       // edge_index[1]

    char* ws = (char*)d_ws;
    size_t o = 0;
    auto alloc = [&](size_t bytes) -> void* {
        void* p = ws + o;
        o = (o + bytes + 255) & ~(size_t)255;
        return p;
    };
    int*   deg  = (int*)alloc((size_t)NN * 4);
    int*   offs = (int*)alloc((size_t)NN * 4);
    int*   cur  = (int*)alloc((size_t)NN * 4);
    int*   csr  = (int*)alloc((size_t)NE * 4);
    float* mean = (float*)alloc((size_t)NN * 128 * 4);
    float* h    = (float*)alloc((size_t)NN * 128 * 4);

    hipMemsetAsync(deg, 0, (size_t)NN * 4, stream);
    hipMemsetAsync(cur, 0, (size_t)NN * 4, stream);

    k_count_deg<<<(NE + 255) / 256, 256, 0, stream>>>(dst, deg);
    k_scan<<<1, 1024, 0, stream>>>(deg, offs);
    k_fill<<<(NE + 255) / 256, 256, 0, stream>>>(src, dst, offs, cur, csr);

    // layer 1
    k_aggregate<<<NN / 4, 256, 0, stream>>>(x, csr, offs, deg, mean);
    k_gemm<128, true><<<(NN + 63) / 64, 256, 0, stream>>>(mean, x, W1l, W1r, b1, h);
    // layer 2
    k_aggregate<<<NN / 4, 256, 0, stream>>>(h, csr, offs, deg, mean);
    k_gemm<64, false><<<(NN + 63) / 64, 256, 0, stream>>>(mean, h, W2l, W2r, b2, out);

    k_logsoftmax<<<NN / 4, 256, 0, stream>>>(out);
}

// Round 2
// 713.286 us; speedup vs baseline: 1.2412x; 1.2412x over previous
//
#include <hip/hip_runtime.h>
#include <math.h>

#define NN 100000
#define NE 1600000
#define SCAN_CH 1024
#define SCAN_NBLK ((NN + SCAN_CH - 1) / SCAN_CH)   // 98

// ---------------- helpers ----------------
static __device__ __forceinline__ void fma4(float4& c, float a, const float4& w) {
    c.x += a * w.x; c.y += a * w.y; c.z += a * w.z; c.w += a * w.w;
}

// ---------------- CSR build ----------------
__global__ void k_count_deg(const int* __restrict__ dst, int* __restrict__ deg) {
    int e = blockIdx.x * blockDim.x + threadIdx.x;
    if (e < NE) atomicAdd(&deg[dst[e]], 1);
}

// device-wide exclusive scan, stage 1: per-block (1024 elems) local scan + block sum
__global__ __launch_bounds__(256)
void k_block_scan(const int* __restrict__ deg, int* __restrict__ offs, int* __restrict__ bsum) {
    __shared__ int tsum[256];
    const int b = blockIdx.x, t = threadIdx.x;
    const int base = b * SCAN_CH + t * 4;
    int v[4]; int s = 0;
    #pragma unroll
    for (int i = 0; i < 4; ++i) { int idx = base + i; v[i] = (idx < NN) ? deg[idx] : 0; s += v[i]; }
    tsum[t] = s;
    __syncthreads();
    for (int d = 1; d < 256; d <<= 1) {
        int u = (t >= d) ? tsum[t - d] : 0;
        __syncthreads();
        tsum[t] += u;
        __syncthreads();
    }
    int excl = tsum[t] - s;   // exclusive prefix within block
    #pragma unroll
    for (int i = 0; i < 4; ++i) { int idx = base + i; if (idx < NN) { offs[idx] = excl; excl += v[i]; } }
    if (t == 255) bsum[b] = tsum[t];
}

// stage 2: exclusive scan of the 98 block sums (single tiny block)
__global__ void k_scan_sums(int* __restrict__ bsum) {
    __shared__ int s[128];
    int t = threadIdx.x;
    int v = (t < SCAN_NBLK) ? bsum[t] : 0;
    s[t] = v;
    __syncthreads();
    for (int d = 1; d < 128; d <<= 1) {
        int u = (t >= d) ? s[t - d] : 0;
        __syncthreads();
        s[t] += u;
        __syncthreads();
    }
    if (t < SCAN_NBLK) bsum[t] = s[t] - v;
}

// stage 3: add block base
__global__ __launch_bounds__(256)
void k_add_base(int* __restrict__ offs, const int* __restrict__ bsum) {
    int i = blockIdx.x * 256 + threadIdx.x;
    if (i < NN) offs[i] += bsum[i >> 10];
}

__global__ void k_fill(const int* __restrict__ src, const int* __restrict__ dst,
                       const int* __restrict__ offs, int* __restrict__ cur,
                       int* __restrict__ csr) {
    int e = blockIdx.x * blockDim.x + threadIdx.x;
    if (e < NE) {
        int d = dst[e];
        int p = atomicAdd(&cur[d], 1);
        csr[offs[d] + p] = src[e];
    }
}

// ---------------- mean aggregation: one wave per node ----------------
__global__ __launch_bounds__(256)
void k_aggregate(const float* __restrict__ feat, const int* __restrict__ csr,
                 const int* __restrict__ offs, const int* __restrict__ deg,
                 float* __restrict__ outmean) {
    int wid = threadIdx.x >> 6;
    int lane = threadIdx.x & 63;
    int node = blockIdx.x * 4 + wid;
    if (node >= NN) return;
    int off = offs[node];
    int dg = deg[node];
    float ax = 0.f, ay = 0.f;
    const float2* f2 = (const float2*)feat;
    for (int j = 0; j < dg; ++j) {
        int s = csr[off + j];
        float2 v = f2[(size_t)s * 64 + lane];
        ax += v.x; ay += v.y;
    }
    float inv = 1.0f / (float)(dg > 0 ? dg : 1);
    float2* o2 = (float2*)outmean;
    o2[(size_t)node * 64 + lane] = make_float2(ax * inv, ay * inv);
}

// ---------------- fused dual GEMM: out = Am@Wl + Ax@Wr + bias (+relu) ----------------
// M=NN, K=128, N=BN (128 or 64). Block: 64 rows x BN cols, 256 threads.
template <int BN, bool RELU>
__global__ __launch_bounds__(256)
void k_gemm(const float* __restrict__ Am, const float* __restrict__ Ax,
            const float* __restrict__ Wl, const float* __restrict__ Wr,
            const float* __restrict__ bias, float* __restrict__ out) {
    constexpr int NH = BN / 64;   // column halves per thread
    constexpr int F  = BN / 8;    // floats of W loaded per thread per chunk
    __shared__ float Alds[64][33];
    __shared__ float Wlds[32][BN];

    const int tid = threadIdx.x;
    const int tx = tid & 15;      // 16 col groups
    const int ty = tid >> 4;      // 16 row groups
    const int row0 = blockIdx.x * 64;

    float4 acc[4][NH];
    #pragma unroll
    for (int i = 0; i < 4; ++i)
        #pragma unroll
        for (int hh = 0; hh < NH; ++hh) acc[i][hh] = make_float4(0.f, 0.f, 0.f, 0.f);

    const int lr = tid >> 2;          // A-load row 0..63
    const int lc = (tid & 3) * 8;     // A-load col 0/8/16/24
    const int wk = tid >> 3;          // W-load row 0..31
    const int wc = (tid & 7) * F;     // W-load col

    for (int s = 0; s < 2; ++s) {
        const float* __restrict__ A = s ? Ax : Am;
        const float* __restrict__ W = s ? Wr : Wl;
        for (int kc = 0; kc < 128; kc += 32) {
            float4 a0 = make_float4(0.f,0.f,0.f,0.f), a1 = a0;
            int grow = row0 + lr;
            if (grow < NN) {
                const float* p = &A[(size_t)grow * 128 + kc + lc];
                a0 = *(const float4*)p;
                a1 = *(const float4*)(p + 4);
            }
            float4 wv[F / 4];
            {
                const float* wp = &W[(size_t)(wk + kc) * BN + wc];
                #pragma unroll
                for (int j = 0; j < F / 4; ++j) wv[j] = *(const float4*)(wp + 4 * j);
            }
            __syncthreads();  // previous chunk's LDS reads done before overwrite
            Alds[lr][lc+0]=a0.x; Alds[lr][lc+1]=a0.y; Alds[lr][lc+2]=a0.z; Alds[lr][lc+3]=a0.w;
            Alds[lr][lc+4]=a1.x; Alds[lr][lc+5]=a1.y; Alds[lr][lc+6]=a1.z; Alds[lr][lc+7]=a1.w;
            #pragma unroll
            for (int j = 0; j < F / 4; ++j) *(float4*)&Wlds[wk][wc + 4 * j] = wv[j];
            __syncthreads();
            #pragma unroll
            for (int kk = 0; kk < 32; ++kk) {
                float r0 = Alds[ty*4+0][kk];
                float r1 = Alds[ty*4+1][kk];
                float r2 = Alds[ty*4+2][kk];
                float r3 = Alds[ty*4+3][kk];
                #pragma unroll
                for (int hh = 0; hh < NH; ++hh) {
                    float4 w = *(const float4*)&Wlds[kk][hh*64 + tx*4];
                    fma4(acc[0][hh], r0, w);
                    fma4(acc[1][hh], r1, w);
                    fma4(acc[2][hh], r2, w);
                    fma4(acc[3][hh], r3, w);
                }
            }
        }
    }
    // epilogue
    #pragma unroll
    for (int hh = 0; hh < NH; ++hh) {
        float4 b = *(const float4*)&bias[hh*64 + tx*4];
        #pragma unroll
        for (int i = 0; i < 4; ++i) {
            int r = row0 + ty*4 + i;
            if (r < NN) {
                float4 v = acc[i][hh];
                v.x += b.x; v.y += b.y; v.z += b.z; v.w += b.w;
                if (RELU) {
                    v.x = fmaxf(v.x, 0.f); v.y = fmaxf(v.y, 0.f);
                    v.z = fmaxf(v.z, 0.f); v.w = fmaxf(v.w, 0.f);
                }
                *(float4*)&out[(size_t)r * BN + hh*64 + tx*4] = v;
            }
        }
    }
}

// ---------------- log_softmax over 64 cols, one wave per row ----------------
__global__ __launch_bounds__(256)
void k_logsoftmax(float* __restrict__ out) {
    int wid = threadIdx.x >> 6, lane = threadIdx.x & 63;
    int row = blockIdx.x * 4 + wid;
    if (row >= NN) return;
    float v = out[(size_t)row * 64 + lane];
    float m = v;
    #pragma unroll
    for (int d = 32; d >= 1; d >>= 1) m = fmaxf(m, __shfl_xor(m, d));
    float ev = __expf(v - m);
    float ssum = ev;
    #pragma unroll
    for (int d = 32; d >= 1; d >>= 1) ssum += __shfl_xor(ssum, d);
    out[(size_t)row * 64 + lane] = v - m - logf(ssum);
}

// ---------------- launch ----------------
extern "C" void kernel_launch(void* const* d_in, const int* in_sizes, int n_in,
                              void* d_out, int out_size, void* d_ws, size_t ws_size,
                              hipStream_t stream) {
    const float* x   = (const float*)d_in[0];
    const int* edges = (const int*)d_in[1];
    const float* W1l = (const float*)d_in[2];
    const float* b1  = (const float*)d_in[3];
    const float* W1r = (const float*)d_in[4];
    const float* W2l = (const float*)d_in[5];
    const float* b2  = (const float*)d_in[6];
    const float* W2r = (const float*)d_in[7];
    float* out = (float*)d_out;

    const int* src = edges;            // edge_index[0]
    const int* dst = edges + NE;       // edge_index[1]

    char* ws = (char*)d_ws;
    size_t o = 0;
    auto alloc = [&](size_t bytes) -> void* {
        void* p = ws + o;
        o = (o + bytes + 255) & ~(size_t)255;
        return p;
    };
    int*   deg  = (int*)alloc((size_t)NN * 4);
    int*   offs = (int*)alloc((size_t)NN * 4);
    int*   cur  = (int*)alloc((size_t)NN * 4);
    int*   bsum = (int*)alloc((size_t)SCAN_NBLK * 4);
    int*   csr  = (int*)alloc((size_t)NE * 4);
    float* mean = (float*)alloc((size_t)NN * 128 * 4);
    float* h    = (float*)alloc((size_t)NN * 128 * 4);

    hipMemsetAsync(deg, 0, (size_t)NN * 4, stream);
    hipMemsetAsync(cur, 0, (size_t)NN * 4, stream);

    k_count_deg<<<(NE + 255) / 256, 256, 0, stream>>>(dst, deg);
    k_block_scan<<<SCAN_NBLK, 256, 0, stream>>>(deg, offs, bsum);
    k_scan_sums<<<1, 128, 0, stream>>>(bsum);
    k_add_base<<<(NN + 255) / 256, 256, 0, stream>>>(offs, bsum);
    k_fill<<<(NE + 255) / 256, 256, 0, stream>>>(src, dst, offs, cur, csr);

    // layer 1
    k_aggregate<<<NN / 4, 256, 0, stream>>>(x, csr, offs, deg, mean);
    k_gemm<128, true><<<(NN + 63) / 64, 256, 0, stream>>>(mean, x, W1l, W1r, b1, h);
    // layer 2
    k_aggregate<<<NN / 4, 256, 0, stream>>>(h, csr, offs, deg, mean);
    k_gemm<64, false><<<(NN + 63) / 64, 256, 0, stream>>>(mean, h, W2l, W2r, b2, out);

    k_logsoftmax<<<NN / 4, 256, 0, stream>>>(out);
}

// Round 3
// 627.289 us; speedup vs baseline: 1.4114x; 1.1371x over previous
//
#include <hip/hip_runtime.h>
#include <math.h>

#define NN 100000
#define NE 1600000
#define SCAN_CH 1024
#define SCAN_NBLK ((NN + SCAN_CH - 1) / SCAN_CH)   // 98

// ---------------- helpers ----------------
static __device__ __forceinline__ void fma4(float4& c, float a, const float4& w) {
    c.x += a * w.x; c.y += a * w.y; c.z += a * w.z; c.w += a * w.w;
}

// ---------------- CSR build ----------------
__global__ void k_count_deg(const int* __restrict__ dst, int* __restrict__ deg) {
    int e = blockIdx.x * blockDim.x + threadIdx.x;
    if (e < NE) atomicAdd(&deg[dst[e]], 1);
}

// device-wide exclusive scan, stage 1: per-block (1024 elems) local scan + block sum
__global__ __launch_bounds__(256)
void k_block_scan(const int* __restrict__ deg, int* __restrict__ offs, int* __restrict__ bsum) {
    __shared__ int tsum[256];
    const int b = blockIdx.x, t = threadIdx.x;
    const int base = b * SCAN_CH + t * 4;
    int v[4]; int s = 0;
    #pragma unroll
    for (int i = 0; i < 4; ++i) { int idx = base + i; v[i] = (idx < NN) ? deg[idx] : 0; s += v[i]; }
    tsum[t] = s;
    __syncthreads();
    for (int d = 1; d < 256; d <<= 1) {
        int u = (t >= d) ? tsum[t - d] : 0;
        __syncthreads();
        tsum[t] += u;
        __syncthreads();
    }
    int excl = tsum[t] - s;   // exclusive prefix within block
    #pragma unroll
    for (int i = 0; i < 4; ++i) { int idx = base + i; if (idx < NN) { offs[idx] = excl; excl += v[i]; } }
    if (t == 255) bsum[b] = tsum[t];
}

// stage 2: exclusive scan of the 98 block sums (single tiny block)
__global__ void k_scan_sums(int* __restrict__ bsum) {
    __shared__ int s[128];
    int t = threadIdx.x;
    int v = (t < SCAN_NBLK) ? bsum[t] : 0;
    s[t] = v;
    __syncthreads();
    for (int d = 1; d < 128; d <<= 1) {
        int u = (t >= d) ? s[t - d] : 0;
        __syncthreads();
        s[t] += u;
        __syncthreads();
    }
    if (t < SCAN_NBLK) bsum[t] = s[t] - v;
}

// stage 3: add block base
__global__ __launch_bounds__(256)
void k_add_base(int* __restrict__ offs, const int* __restrict__ bsum) {
    int i = blockIdx.x * 256 + threadIdx.x;
    if (i < NN) offs[i] += bsum[i >> 10];
}

__global__ void k_fill(const int* __restrict__ src, const int* __restrict__ dst,
                       const int* __restrict__ offs, int* __restrict__ cur,
                       int* __restrict__ csr) {
    int e = blockIdx.x * blockDim.x + threadIdx.x;
    if (e < NE) {
        int d = dst[e];
        int p = atomicAdd(&cur[d], 1);
        csr[offs[d] + p] = src[e];
    }
}

// ---------------- mean aggregation: one wave per node, 2 edges/iter, unroll 4 ----------------
// Each lane loads float4; lanes 0-31 cover edge A's 128-col row, lanes 32-63 edge B's.
// 8 edges (4 KB) outstanding per wave -> latency-hiding via MLP.
__global__ __launch_bounds__(256)
void k_aggregate(const float* __restrict__ feat, const int* __restrict__ csr,
                 const int* __restrict__ offs, const int* __restrict__ deg,
                 float* __restrict__ outmean) {
    const int wid = threadIdx.x >> 6;
    const int lane = threadIdx.x & 63;
    const int half = lane >> 5;       // 0: even edge, 1: odd edge
    const int l5 = lane & 31;         // float4 index within row (32 x 16B = 512B)
    const int node = blockIdx.x * 4 + wid;
    if (node >= NN) return;
    int off = __builtin_amdgcn_readfirstlane(offs[node]);
    int dg  = __builtin_amdgcn_readfirstlane(deg[node]);

    const float4* __restrict__ f4 = (const float4*)feat;
    float4 acc = make_float4(0.f, 0.f, 0.f, 0.f);

    int j = 0;
    for (; j + 8 <= dg; j += 8) {
        int e[8];
        #pragma unroll
        for (int k = 0; k < 8; ++k) e[k] = csr[off + j + k];
        float4 v[4];
        #pragma unroll
        for (int k = 0; k < 4; ++k) {
            int s = half ? e[2 * k + 1] : e[2 * k];
            v[k] = f4[(size_t)s * 32 + l5];
        }
        #pragma unroll
        for (int k = 0; k < 4; ++k) {
            acc.x += v[k].x; acc.y += v[k].y; acc.z += v[k].z; acc.w += v[k].w;
        }
    }
    for (; j + 2 <= dg; j += 2) {
        int e0 = csr[off + j], e1 = csr[off + j + 1];
        int s = half ? e1 : e0;
        float4 v = f4[(size_t)s * 32 + l5];
        acc.x += v.x; acc.y += v.y; acc.z += v.z; acc.w += v.w;
    }
    if (j < dg) {   // single leftover edge: only half 0 accumulates it
        int s = csr[off + j];
        if (!half) {
            float4 v = f4[(size_t)s * 32 + l5];
            acc.x += v.x; acc.y += v.y; acc.z += v.z; acc.w += v.w;
        }
    }
    // combine the two half-wave partial sums (lane i += lane i^32)
    acc.x += __shfl_xor(acc.x, 32);
    acc.y += __shfl_xor(acc.y, 32);
    acc.z += __shfl_xor(acc.z, 32);
    acc.w += __shfl_xor(acc.w, 32);

    if (!half) {
        float inv = 1.0f / (float)(dg > 0 ? dg : 1);
        float4 r = make_float4(acc.x * inv, acc.y * inv, acc.z * inv, acc.w * inv);
        ((float4*)outmean)[(size_t)node * 32 + l5] = r;
    }
}

// ---------------- fused dual GEMM: out = Am@Wl + Ax@Wr + bias (+relu) ----------------
// M=NN, K=128, N=BN (128 or 64). Block: 64 rows x BN cols, 256 threads.
template <int BN, bool RELU>
__global__ __launch_bounds__(256)
void k_gemm(const float* __restrict__ Am, const float* __restrict__ Ax,
            const float* __restrict__ Wl, const float* __restrict__ Wr,
            const float* __restrict__ bias, float* __restrict__ out) {
    constexpr int NH = BN / 64;   // column halves per thread
    constexpr int F  = BN / 8;    // floats of W loaded per thread per chunk
    __shared__ float Alds[64][33];
    __shared__ float Wlds[32][BN];

    const int tid = threadIdx.x;
    const int tx = tid & 15;      // 16 col groups
    const int ty = tid >> 4;      // 16 row groups
    const int row0 = blockIdx.x * 64;

    float4 acc[4][NH];
    #pragma unroll
    for (int i = 0; i < 4; ++i)
        #pragma unroll
        for (int hh = 0; hh < NH; ++hh) acc[i][hh] = make_float4(0.f, 0.f, 0.f, 0.f);

    const int lr = tid >> 2;          // A-load row 0..63
    const int lc = (tid & 3) * 8;     // A-load col 0/8/16/24
    const int wk = tid >> 3;          // W-load row 0..31
    const int wc = (tid & 7) * F;     // W-load col

    for (int s = 0; s < 2; ++s) {
        const float* __restrict__ A = s ? Ax : Am;
        const float* __restrict__ W = s ? Wr : Wl;
        for (int kc = 0; kc < 128; kc += 32) {
            float4 a0 = make_float4(0.f,0.f,0.f,0.f), a1 = a0;
            int grow = row0 + lr;
            if (grow < NN) {
                const float* p = &A[(size_t)grow * 128 + kc + lc];
                a0 = *(const float4*)p;
                a1 = *(const float4*)(p + 4);
            }
            float4 wv[F / 4];
            {
                const float* wp = &W[(size_t)(wk + kc) * BN + wc];
                #pragma unroll
                for (int j = 0; j < F / 4; ++j) wv[j] = *(const float4*)(wp + 4 * j);
            }
            __syncthreads();  // previous chunk's LDS reads done before overwrite
            Alds[lr][lc+0]=a0.x; Alds[lr][lc+1]=a0.y; Alds[lr][lc+2]=a0.z; Alds[lr][lc+3]=a0.w;
            Alds[lr][lc+4]=a1.x; Alds[lr][lc+5]=a1.y; Alds[lr][lc+6]=a1.z; Alds[lr][lc+7]=a1.w;
            #pragma unroll
            for (int j = 0; j < F / 4; ++j) *(float4*)&Wlds[wk][wc + 4 * j] = wv[j];
            __syncthreads();
            #pragma unroll
            for (int kk = 0; kk < 32; ++kk) {
                float r0 = Alds[ty*4+0][kk];
                float r1 = Alds[ty*4+1][kk];
                float r2 = Alds[ty*4+2][kk];
                float r3 = Alds[ty*4+3][kk];
                #pragma unroll
                for (int hh = 0; hh < NH; ++hh) {
                    float4 w = *(const float4*)&Wlds[kk][hh*64 + tx*4];
                    fma4(acc[0][hh], r0, w);
                    fma4(acc[1][hh], r1, w);
                    fma4(acc[2][hh], r2, w);
                    fma4(acc[3][hh], r3, w);
                }
            }
        }
    }
    // epilogue
    #pragma unroll
    for (int hh = 0; hh < NH; ++hh) {
        float4 b = *(const float4*)&bias[hh*64 + tx*4];
        #pragma unroll
        for (int i = 0; i < 4; ++i) {
            int r = row0 + ty*4 + i;
            if (r < NN) {
                float4 v = acc[i][hh];
                v.x += b.x; v.y += b.y; v.z += b.z; v.w += b.w;
                if (RELU) {
                    v.x = fmaxf(v.x, 0.f); v.y = fmaxf(v.y, 0.f);
                    v.z = fmaxf(v.z, 0.f); v.w = fmaxf(v.w, 0.f);
                }
                *(float4*)&out[(size_t)r * BN + hh*64 + tx*4] = v;
            }
        }
    }
}

// ---------------- log_softmax over 64 cols, one wave per row ----------------
__global__ __launch_bounds__(256)
void k_logsoftmax(float* __restrict__ out) {
    int wid = threadIdx.x >> 6, lane = threadIdx.x & 63;
    int row = blockIdx.x * 4 + wid;
    if (row >= NN) return;
    float v = out[(size_t)row * 64 + lane];
    float m = v;
    #pragma unroll
    for (int d = 32; d >= 1; d >>= 1) m = fmaxf(m, __shfl_xor(m, d));
    float ev = __expf(v - m);
    float ssum = ev;
    #pragma unroll
    for (int d = 32; d >= 1; d >>= 1) ssum += __shfl_xor(ssum, d);
    out[(size_t)row * 64 + lane] = v - m - logf(ssum);
}

// ---------------- launch ----------------
extern "C" void kernel_launch(void* const* d_in, const int* in_sizes, int n_in,
                              void* d_out, int out_size, void* d_ws, size_t ws_size,
                              hipStream_t stream) {
    const float* x   = (const float*)d_in[0];
    const int* edges = (const int*)d_in[1];
    const float* W1l = (const float*)d_in[2];
    const float* b1  = (const float*)d_in[3];
    const float* W1r = (const float*)d_in[4];
    const float* W2l = (const float*)d_in[5];
    const float* b2  = (const float*)d_in[6];
    const float* W2r = (const float*)d_in[7];
    float* out = (float*)d_out;

    const int* src = edges;            // edge_index[0]
    const int* dst = edges + NE;       // edge_index[1]

    char* ws = (char*)d_ws;
    size_t o = 0;
    auto alloc = [&](size_t bytes) -> void* {
        void* p = ws + o;
        o = (o + bytes + 255) & ~(size_t)255;
        return p;
    };
    int*   deg  = (int*)alloc((size_t)NN * 4);
    int*   offs = (int*)alloc((size_t)NN * 4);
    int*   cur  = (int*)alloc((size_t)NN * 4);
    int*   bsum = (int*)alloc((size_t)SCAN_NBLK * 4);
    int*   csr  = (int*)alloc((size_t)NE * 4);
    float* mean = (float*)alloc((size_t)NN * 128 * 4);
    float* h    = (float*)alloc((size_t)NN * 128 * 4);

    hipMemsetAsync(deg, 0, (size_t)NN * 4, stream);
    hipMemsetAsync(cur, 0, (size_t)NN * 4, stream);

    k_count_deg<<<(NE + 255) / 256, 256, 0, stream>>>(dst, deg);
    k_block_scan<<<SCAN_NBLK, 256, 0, stream>>>(deg, offs, bsum);
    k_scan_sums<<<1, 128, 0, stream>>>(bsum);
    k_add_base<<<(NN + 255) / 256, 256, 0, stream>>>(offs, bsum);
    k_fill<<<(NE + 255) / 256, 256, 0, stream>>>(src, dst, offs, cur, csr);

    // layer 1
    k_aggregate<<<NN / 4, 256, 0, stream>>>(x, csr, offs, deg, mean);
    k_gemm<128, true><<<(NN + 63) / 64, 256, 0, stream>>>(mean, x, W1l, W1r, b1, h);
    // layer 2
    k_aggregate<<<NN / 4, 256, 0, stream>>>(h, csr, offs, deg, mean);
    k_gemm<64, false><<<(NN + 63) / 64, 256, 0, stream>>>(mean, h, W2l, W2r, b2, out);

    k_logsoftmax<<<NN / 4, 256, 0, stream>>>(out);
}

// Round 4
// 390.914 us; speedup vs baseline: 2.2648x; 1.6047x over previous
//
#include <hip/hip_runtime.h>
#include <math.h>

#define NN 100000
#define NE 1600000
#define SCAN_CH 1024
#define SCAN_NBLK ((NN + SCAN_CH - 1) / SCAN_CH)   // 98

typedef __attribute__((ext_vector_type(8))) short bf16x8;   // 8 bf16 = 4 VGPR (MFMA A/B frag)
typedef __attribute__((ext_vector_type(8))) unsigned short ush8;
typedef __attribute__((ext_vector_type(4))) float f32x4;    // MFMA C/D frag

static __device__ __forceinline__ float b2f(unsigned short u) {
    return __uint_as_float(((unsigned int)u) << 16);
}
static __device__ __forceinline__ unsigned short f2bf(float f) {
    unsigned int u = __float_as_uint(f);
    u += 0x7fffu + ((u >> 16) & 1u);   // RNE
    return (unsigned short)(u >> 16);
}

// ---------------- conversions ----------------
__global__ __launch_bounds__(256)
void k_cvt_x(const float* __restrict__ in, unsigned short* __restrict__ outb, long total8) {
    long i = (long)blockIdx.x * 256 + threadIdx.x;
    long stride = (long)gridDim.x * 256;
    for (; i < total8; i += stride) {
        const float4* p = (const float4*)(in + i * 8);
        float4 a = p[0], b = p[1];
        ush8 r;
        r[0] = f2bf(a.x); r[1] = f2bf(a.y); r[2] = f2bf(a.z); r[3] = f2bf(a.w);
        r[4] = f2bf(b.x); r[5] = f2bf(b.y); r[6] = f2bf(b.z); r[7] = f2bf(b.w);
        *(ush8*)(outb + i * 8) = r;
    }
}

// W [128, N] f32 -> Wt [N, 128] bf16 (row-major over n)
__global__ __launch_bounds__(256)
void k_cvt_w(const float* __restrict__ W, unsigned short* __restrict__ Wt, int N) {
    int id = blockIdx.x * 256 + threadIdx.x;
    if (id < N * 128) {
        int n = id >> 7, k = id & 127;
        Wt[id] = f2bf(W[k * N + n]);
    }
}

// ---------------- CSR build ----------------
__global__ void k_count_deg(const int* __restrict__ dst, int* __restrict__ deg) {
    int e = blockIdx.x * blockDim.x + threadIdx.x;
    if (e < NE) atomicAdd(&deg[dst[e]], 1);
}

__global__ __launch_bounds__(256)
void k_block_scan(const int* __restrict__ deg, int* __restrict__ offs, int* __restrict__ bsum) {
    __shared__ int tsum[256];
    const int b = blockIdx.x, t = threadIdx.x;
    const int base = b * SCAN_CH + t * 4;
    int v[4]; int s = 0;
    #pragma unroll
    for (int i = 0; i < 4; ++i) { int idx = base + i; v[i] = (idx < NN) ? deg[idx] : 0; s += v[i]; }
    tsum[t] = s;
    __syncthreads();
    for (int d = 1; d < 256; d <<= 1) {
        int u = (t >= d) ? tsum[t - d] : 0;
        __syncthreads();
        tsum[t] += u;
        __syncthreads();
    }
    int excl = tsum[t] - s;
    #pragma unroll
    for (int i = 0; i < 4; ++i) { int idx = base + i; if (idx < NN) { offs[idx] = excl; excl += v[i]; } }
    if (t == 255) bsum[b] = tsum[t];
}

__global__ void k_scan_sums(int* __restrict__ bsum) {
    __shared__ int s[128];
    int t = threadIdx.x;
    int v = (t < SCAN_NBLK) ? bsum[t] : 0;
    s[t] = v;
    __syncthreads();
    for (int d = 1; d < 128; d <<= 1) {
        int u = (t >= d) ? s[t - d] : 0;
        __syncthreads();
        s[t] += u;
        __syncthreads();
    }
    if (t < SCAN_NBLK) bsum[t] = s[t] - v;
}

__global__ __launch_bounds__(256)
void k_add_base(int* __restrict__ offs, const int* __restrict__ bsum) {
    int i = blockIdx.x * 256 + threadIdx.x;
    if (i < NN) offs[i] += bsum[i >> 10];
}

__global__ void k_fill(const int* __restrict__ src, const int* __restrict__ dst,
                       const int* __restrict__ offs, int* __restrict__ cur,
                       int* __restrict__ csr) {
    int e = blockIdx.x * blockDim.x + threadIdx.x;
    if (e < NE) {
        int d = dst[e];
        int p = atomicAdd(&cur[d], 1);
        csr[offs[d] + p] = src[e];
    }
}

// ---------------- bf16 mean aggregation: one wave per node, 4 edges/group-iter ----------------
// Row = 128 bf16 = 256B = 16 lanes x 16B. 4 lane-groups of 16 -> 4 edges in parallel, unroll 2.
__global__ __launch_bounds__(256)
void k_aggregate_bf(const unsigned short* __restrict__ feat, const int* __restrict__ csr,
                    const int* __restrict__ offs, const int* __restrict__ deg,
                    unsigned short* __restrict__ outmean) {
    const int wid = threadIdx.x >> 6, lane = threadIdx.x & 63;
    const int q = lane >> 4, l4 = lane & 15;
    const int node = blockIdx.x * 4 + wid;
    if (node >= NN) return;
    int off = __builtin_amdgcn_readfirstlane(offs[node]);
    int dg  = __builtin_amdgcn_readfirstlane(deg[node]);
    const ush8* __restrict__ f8 = (const ush8*)feat;
    float acc[8];
    #pragma unroll
    for (int i = 0; i < 8; ++i) acc[i] = 0.f;
    int j = 0;
    for (; j + 8 <= dg; j += 8) {
        int e0 = csr[off + j + q];
        int e1 = csr[off + j + 4 + q];
        ush8 v0 = f8[(size_t)e0 * 16 + l4];
        ush8 v1 = f8[(size_t)e1 * 16 + l4];
        #pragma unroll
        for (int i = 0; i < 8; ++i) acc[i] += b2f(v0[i]) + b2f(v1[i]);
    }
    for (; j + 4 <= dg; j += 4) {
        int e0 = csr[off + j + q];
        ush8 v0 = f8[(size_t)e0 * 16 + l4];
        #pragma unroll
        for (int i = 0; i < 8; ++i) acc[i] += b2f(v0[i]);
    }
    int rem = dg - j;
    if (q < rem) {
        int e0 = csr[off + j + q];
        ush8 v0 = f8[(size_t)e0 * 16 + l4];
        #pragma unroll
        for (int i = 0; i < 8; ++i) acc[i] += b2f(v0[i]);
    }
    #pragma unroll
    for (int i = 0; i < 8; ++i) {
        acc[i] += __shfl_xor(acc[i], 16);
        acc[i] += __shfl_xor(acc[i], 32);
    }
    if (q == 0) {
        float inv = 1.0f / (float)(dg > 0 ? dg : 1);
        ush8 r;
        #pragma unroll
        for (int i = 0; i < 8; ++i) r[i] = f2bf(acc[i] * inv);
        ((ush8*)outmean)[(size_t)node * 16 + l4] = r;
    }
}

// ---------------- MFMA dual GEMM: out = Am@Wl + Ax@Wr + bias (+relu) ----------------
// A: [NN,128] bf16. Wt: [BN,128] bf16 (pre-transposed). Block: 128 rows x BN cols, 4 waves.
// mfma_f32_16x16x32_bf16; A-frag A[m=lane&15][k=(lane>>4)*8+i]; C/D col=lane&15,row=(lane>>4)*4+reg.
template <int BN, bool RELU, bool OUTBF>
__global__ __launch_bounds__(256)
void k_gemm_mfma(const unsigned short* __restrict__ Am, const unsigned short* __restrict__ Ax,
                 const unsigned short* __restrict__ Wtl, const unsigned short* __restrict__ Wtr,
                 const float* __restrict__ bias, void* __restrict__ outp) {
    constexpr int BM = 128;
    constexpr int WAVES_N = BN / 64;          // 2 (BN=128) or 1 (BN=64)
    constexpr int WAVES_M = 4 / WAVES_N;      // 2 or 4
    constexpr int MR = BM / (WAVES_M * 16);   // 4 or 2
    constexpr int NR = 4;                     // 64 cols per wave
    __shared__ __align__(16) short As[BM * 40];   // 80B row stride -> uniform banks
    __shared__ __align__(16) short Ws[BN * 40];

    const int tid = threadIdx.x;
    const int wave = tid >> 6, lane = tid & 63;
    const int l15 = lane & 15, kg = lane >> 4;
    const int wc = wave % WAVES_N, wr = wave / WAVES_N;
    const int rowbase = wr * MR * 16;
    const int colbase = wc * 64;
    const int row0 = blockIdx.x * BM;

    f32x4 acc[MR][NR];
    #pragma unroll
    for (int mr = 0; mr < MR; ++mr)
        #pragma unroll
        for (int nr = 0; nr < NR; ++nr) acc[mr][nr] = (f32x4){0.f, 0.f, 0.f, 0.f};

    for (int s = 0; s < 2; ++s) {
        const unsigned short* __restrict__ A  = s ? Ax : Am;
        const unsigned short* __restrict__ Wt = s ? Wtr : Wtl;
        for (int kc = 0; kc < 128; kc += 32) {
            __syncthreads();
            #pragma unroll
            for (int i = 0; i < (BM * 4) / 256; ++i) {
                int c = tid + 256 * i; int r = c >> 2, g = c & 3;
                ush8 v = {0, 0, 0, 0, 0, 0, 0, 0};
                int grow = row0 + r;
                if (grow < NN) v = *(const ush8*)&A[(size_t)grow * 128 + kc + g * 8];
                *(ush8*)&As[r * 40 + g * 8] = v;
            }
            #pragma unroll
            for (int i = 0; i < (BN * 4) / 256; ++i) {
                int c = tid + 256 * i; int n = c >> 2, g = c & 3;
                *(ush8*)&Ws[n * 40 + g * 8] = *(const ush8*)&Wt[n * 128 + kc + g * 8];
            }
            __syncthreads();
            bf16x8 af[MR], bfr[NR];
            #pragma unroll
            for (int mr = 0; mr < MR; ++mr)
                af[mr] = *(const bf16x8*)&As[(rowbase + mr * 16 + l15) * 40 + kg * 8];
            #pragma unroll
            for (int nr = 0; nr < NR; ++nr)
                bfr[nr] = *(const bf16x8*)&Ws[(colbase + nr * 16 + l15) * 40 + kg * 8];
            #pragma unroll
            for (int mr = 0; mr < MR; ++mr)
                #pragma unroll
                for (int nr = 0; nr < NR; ++nr)
                    acc[mr][nr] = __builtin_amdgcn_mfma_f32_16x16x32_bf16(
                        af[mr], bfr[nr], acc[mr][nr], 0, 0, 0);
        }
    }
    // epilogue
    const int r4 = kg * 4;
    #pragma unroll
    for (int mr = 0; mr < MR; ++mr) {
        #pragma unroll
        for (int nr = 0; nr < NR; ++nr) {
            int col = colbase + nr * 16 + l15;
            float bv = bias[col];
            #pragma unroll
            for (int j = 0; j < 4; ++j) {
                int row = row0 + rowbase + mr * 16 + r4 + j;
                if (row < NN) {
                    float v = acc[mr][nr][j] + bv;
                    if (RELU) v = fmaxf(v, 0.f);
                    if (OUTBF) ((unsigned short*)outp)[(size_t)row * BN + col] = f2bf(v);
                    else       ((float*)outp)[(size_t)row * BN + col] = v;
                }
            }
        }
    }
}

// ---------------- log_softmax over 64 cols, one wave per row ----------------
__global__ __launch_bounds__(256)
void k_logsoftmax(float* __restrict__ out) {
    int wid = threadIdx.x >> 6, lane = threadIdx.x & 63;
    int row = blockIdx.x * 4 + wid;
    if (row >= NN) return;
    float v = out[(size_t)row * 64 + lane];
    float m = v;
    #pragma unroll
    for (int d = 32; d >= 1; d >>= 1) m = fmaxf(m, __shfl_xor(m, d));
    float ev = __expf(v - m);
    float ssum = ev;
    #pragma unroll
    for (int d = 32; d >= 1; d >>= 1) ssum += __shfl_xor(ssum, d);
    out[(size_t)row * 64 + lane] = v - m - logf(ssum);
}

// ---------------- launch ----------------
extern "C" void kernel_launch(void* const* d_in, const int* in_sizes, int n_in,
                              void* d_out, int out_size, void* d_ws, size_t ws_size,
                              hipStream_t stream) {
    const float* x   = (const float*)d_in[0];
    const int* edges = (const int*)d_in[1];
    const float* W1l = (const float*)d_in[2];
    const float* b1  = (const float*)d_in[3];
    const float* W1r = (const float*)d_in[4];
    const float* W2l = (const float*)d_in[5];
    const float* b2  = (const float*)d_in[6];
    const float* W2r = (const float*)d_in[7];
    float* out = (float*)d_out;

    const int* src = edges;            // edge_index[0]
    const int* dst = edges + NE;       // edge_index[1]

    char* ws = (char*)d_ws;
    size_t o = 0;
    auto alloc = [&](size_t bytes) -> void* {
        void* p = ws + o;
        o = (o + bytes + 255) & ~(size_t)255;
        return p;
    };
    int* deg  = (int*)alloc((size_t)NN * 4);
    int* offs = (int*)alloc((size_t)NN * 4);
    int* cur  = (int*)alloc((size_t)NN * 4);
    int* bsum = (int*)alloc((size_t)SCAN_NBLK * 4);
    int* csr  = (int*)alloc((size_t)NE * 4);
    unsigned short* xb    = (unsigned short*)alloc((size_t)NN * 128 * 2);
    unsigned short* meanb = (unsigned short*)alloc((size_t)NN * 128 * 2);
    unsigned short* hb    = (unsigned short*)alloc((size_t)NN * 128 * 2);
    unsigned short* Wt1l  = (unsigned short*)alloc(128 * 128 * 2);
    unsigned short* Wt1r  = (unsigned short*)alloc(128 * 128 * 2);
    unsigned short* Wt2l  = (unsigned short*)alloc(64 * 128 * 2);
    unsigned short* Wt2r  = (unsigned short*)alloc(64 * 128 * 2);

    hipMemsetAsync(deg, 0, (size_t)NN * 4, stream);
    hipMemsetAsync(cur, 0, (size_t)NN * 4, stream);

    // conversions
    k_cvt_x<<<2048, 256, 0, stream>>>(x, xb, (long)NN * 128 / 8);
    k_cvt_w<<<(128 * 128 + 255) / 256, 256, 0, stream>>>(W1l, Wt1l, 128);
    k_cvt_w<<<(128 * 128 + 255) / 256, 256, 0, stream>>>(W1r, Wt1r, 128);
    k_cvt_w<<<(64 * 128 + 255) / 256, 256, 0, stream>>>(W2l, Wt2l, 64);
    k_cvt_w<<<(64 * 128 + 255) / 256, 256, 0, stream>>>(W2r, Wt2r, 64);

    // CSR build
    k_count_deg<<<(NE + 255) / 256, 256, 0, stream>>>(dst, deg);
    k_block_scan<<<SCAN_NBLK, 256, 0, stream>>>(deg, offs, bsum);
    k_scan_sums<<<1, 128, 0, stream>>>(bsum);
    k_add_base<<<(NN + 255) / 256, 256, 0, stream>>>(offs, bsum);
    k_fill<<<(NE + 255) / 256, 256, 0, stream>>>(src, dst, offs, cur, csr);

    const int GEMM_GRID = (NN + 127) / 128;   // 782
    // layer 1
    k_aggregate_bf<<<NN / 4, 256, 0, stream>>>(xb, csr, offs, deg, meanb);
    k_gemm_mfma<128, true, true><<<GEMM_GRID, 256, 0, stream>>>(meanb, xb, Wt1l, Wt1r, b1, hb);
    // layer 2
    k_aggregate_bf<<<NN / 4, 256, 0, stream>>>(hb, csr, offs, deg, meanb);
    k_gemm_mfma<64, false, false><<<GEMM_GRID, 256, 0, stream>>>(meanb, hb, Wt2l, Wt2r, b2, out);

    k_logsoftmax<<<NN / 4, 256, 0, stream>>>(out);
}